// Round 18
// baseline (452.887 us; speedup 1.0000x reference)
//
#include <hip/hip_runtime.h>
#include <math.h>

#define BB 64
#define TT 4096
#define CC 128
#define NQ 64
#define TCH2 128   // t-rows per apply block (c is split 2-way)
#define NBW 1024   // bins for wave-private select
#define PCAP 1024  // pool slots per wave
#define NBKT_G 1024

// ---------------- Kernel 0: transpose x (B,T,C) -> xT (B,C,T) ----------------
__global__ __launch_bounds__(256) void transpose_kernel(const float* __restrict__ x,
                                                        float* __restrict__ xT) {
    __shared__ float tile[64][65];
    const int cb = blockIdx.x;
    const int tb = blockIdx.y;
    const int b  = blockIdx.z;
    const int tid = threadIdx.x;
    const int q = tid >> 6;
    const int l = tid & 63;

    const float* xs = x + ((size_t)b * TT + (size_t)tb * 64) * CC + (size_t)cb * 64;
    #pragma unroll
    for (int j = 0; j < 16; ++j) {
        int tl = q * 16 + j;
        tile[tl][l] = xs[(size_t)tl * CC + l];
    }
    __syncthreads();
    float* xd = xT + ((size_t)b * CC + (size_t)cb * 64) * TT + (size_t)tb * 64;
    #pragma unroll
    for (int j = 0; j < 16; ++j) {
        int cl = q * 16 + j;
        xd[(size_t)cl * TT + l] = tile[l][cl];
    }
}

// ---------------- Kernel 1 (fast path): WAVE-private bucket select ----------------
// One row per WAVE; 4 waves/block, zero __syncthreads. Wave-private hist/pool
// in LDS; single-wave shfl scans; lane q computes quantile q directly.
// hist[] (u32 counts) is reused as the bin->fid table after the scan.
__global__ __launch_bounds__(256) void bucket_quantile_W(const float* __restrict__ xT,
                                                         float* __restrict__ qtab) {
    __shared__ unsigned       histW[4][NBW];   // counts -> fid (0xFFFFFFFF = none)
    __shared__ float          poolW[4][PCAP];  // flagged elements, compacted
    __shared__ unsigned       rankW[4][128];   // (bin<<12) | k
    __shared__ unsigned       curW[4][132];    // fid -> running cursor
    __shared__ unsigned short pbW[4][132];     // fid -> pool base
    __shared__ unsigned short lenW[4][132];    // fid -> segment length

    const int tid = threadIdx.x;
    const int wid = tid >> 6, lane = tid & 63;
    const int row = blockIdx.x * 4 + wid;      // = b*CC + c
    const float* xrow = xT + (size_t)row * TT;
    unsigned* hist = histW[wid];

    // load 64 elements per lane (16 x float4, coalesced within the wave)
    float4 vv[16];
    #pragma unroll
    for (int j = 0; j < 16; ++j)
        vv[j] = ((const float4*)xrow)[j * 64 + lane];

    // zero own 16 bins
    #pragma unroll
    for (int q = 0; q < 4; ++q)
        *(uint4*)&hist[lane * 16 + q * 4] = make_uint4(0u, 0u, 0u, 0u);
    __threadfence_block();

    // histogram: bucket = clamp(trunc((v+5)*102.4), 0, 1023) — monotone in v
    #pragma unroll
    for (int j = 0; j < 16; ++j) {
        int b0 = (int)((vv[j].x + 5.0f) * 102.4f); b0 = b0 < 0 ? 0 : (b0 > NBW-1 ? NBW-1 : b0);
        int b1 = (int)((vv[j].y + 5.0f) * 102.4f); b1 = b1 < 0 ? 0 : (b1 > NBW-1 ? NBW-1 : b1);
        int b2 = (int)((vv[j].z + 5.0f) * 102.4f); b2 = b2 < 0 ? 0 : (b2 > NBW-1 ? NBW-1 : b2);
        int b3 = (int)((vv[j].w + 5.0f) * 102.4f); b3 = b3 < 0 ? 0 : (b3 > NBW-1 ? NBW-1 : b3);
        atomicAdd(&hist[b0], 1u); atomicAdd(&hist[b1], 1u);
        atomicAdd(&hist[b2], 1u); atomicAdd(&hist[b3], 1u);
    }
    __threadfence_block();

    // wave exclusive scan over 1024 bins (lane owns 16 consecutive)
    unsigned carr[17];
    {
        uint4 h0 = *(uint4*)&hist[lane * 16];
        uint4 h1 = *(uint4*)&hist[lane * 16 + 4];
        uint4 h2 = *(uint4*)&hist[lane * 16 + 8];
        uint4 h3 = *(uint4*)&hist[lane * 16 + 12];
        unsigned hh[16] = { h0.x,h0.y,h0.z,h0.w, h1.x,h1.y,h1.z,h1.w,
                            h2.x,h2.y,h2.z,h2.w, h3.x,h3.y,h3.z,h3.w };
        unsigned S = 0;
        #pragma unroll
        for (int i = 0; i < 16; ++i) S += hh[i];
        unsigned incl = S;
        #pragma unroll
        for (int off = 1; off < 64; off <<= 1) {
            unsigned n = __shfl_up(incl, off, 64);
            if (lane >= off) incl += n;
        }
        carr[0] = incl - S;
        #pragma unroll
        for (int i = 0; i < 16; ++i) carr[i + 1] = carr[i] + hh[i];
    }

    // mark bins containing target ranks 64q+31 / 64q+32; record (bin<<12)|k
    unsigned flg = 0, myLen = 0, myCnt = 0;
    #pragma unroll
    for (int bi = 0; bi < 16; ++bi) {
        const int cs = (int)carr[bi], ce = (int)carr[bi + 1];
        if (ce > cs) {
            int t0 = cs - 32;
            int q0 = t0 < 0 ? 0 : (t0 >> 6);
            int q1 = (ce >> 6); if (q1 > 63) q1 = 63;
            bool any = false;
            for (int q = q0; q <= q1; ++q) {
                int r1 = (q << 6) + 31, r2 = r1 + 1;
                bool i1 = (r1 >= cs) && (r1 < ce);
                bool i2 = (r2 >= cs) && (r2 < ce);
                unsigned sbin = (unsigned)(lane * 16 + bi);
                if (i1) rankW[wid][2 * q]     = (sbin << 12) | (unsigned)(r1 - cs);
                if (i2) rankW[wid][2 * q + 1] = (sbin << 12) | (unsigned)(r2 - cs);
                any |= (i1 || i2);
            }
            if (any) { flg |= (1u << bi); myLen += (unsigned)(ce - cs); myCnt++; }
        }
    }

    // packed wave scan (len<<16 | cnt) -> compact pool slot assignment
    {
        unsigned pk = (myLen << 16) | myCnt;
        unsigned incl2 = pk;
        #pragma unroll
        for (int off = 1; off < 64; off <<= 1) {
            unsigned n = __shfl_up(incl2, off, 64);
            if (lane >= off) incl2 += n;
        }
        unsigned b2 = incl2 - pk;
        unsigned lenB = b2 >> 16, cntB = b2 & 0xFFFFu;
        #pragma unroll
        for (int bi = 0; bi < 16; ++bi) {
            int s = lane * 16 + bi;
            if (flg & (1u << bi)) {
                unsigned L = carr[bi + 1] - carr[bi];
                hist[s] = cntB;                       // bin -> fid (reuse)
                pbW[wid][cntB]  = (unsigned short)lenB;
                lenW[wid][cntB] = (unsigned short)L;
                curW[wid][cntB] = lenB;
                cntB++;
                lenB += L;
            } else {
                hist[s] = 0xFFFFFFFFu;                // no fid
            }
        }
    }
    __threadfence_block();

    // filtered scatter from registers: only flagged-bin elements (~18%)
    #pragma unroll
    for (int j = 0; j < 16; ++j) {
        float vs[4] = { vv[j].x, vv[j].y, vv[j].z, vv[j].w };
        #pragma unroll
        for (int e = 0; e < 4; ++e) {
            int bk = (int)((vs[e] + 5.0f) * 102.4f);
            bk = bk < 0 ? 0 : (bk > NBW - 1 ? NBW - 1 : bk);
            unsigned fid = hist[bk];
            if (fid != 0xFFFFFFFFu) {
                unsigned p = atomicAdd(&curW[wid][fid], 1u);
                if (p < (unsigned)PCAP) poolW[wid][p] = vs[e];
            }
        }
    }
    __threadfence_block();

    // selection: lane q computes both ranks of quantile q (no shfl needed)
    {
        float ans[2];
        #pragma unroll
        for (int hk = 0; hk < 2; ++hk) {
            const unsigned info = rankW[wid][2 * lane + hk];
            const int sbin = (int)(info >> 12);
            const int k = (int)(info & 0xFFFu);
            const unsigned fid = hist[sbin];
            const int L = (int)lenW[wid][fid];
            const float* seg = &poolW[wid][pbW[wid][fid]];
            float a = 0.0f;
            for (int i = 0; i < L; ++i) {
                float vi = seg[i];
                int rk = 0;
                for (int jj = 0; jj < L; ++jj) {
                    float vj = seg[jj];
                    rk += (vj < vi) || (vj == vi && jj < i);   // index tie-break
                }
                if (rk == k) { a = vi; break; }
            }
            ans[hk] = a;
        }
        qtab[(size_t)row * NQ + lane] = (ans[0] + ans[1]) * 0.5f;  // frac = 0.5
    }
}

// ---------------- Kernel 1 (fallback, proven R7): strided-gather bucket select ----------------
__global__ __launch_bounds__(256) void bucket_quantile_G(const float* __restrict__ x,
                                                         float* __restrict__ qtab) {
    __shared__ unsigned hist[NBKT_G];
    __shared__ unsigned cum[NBKT_G];
    __shared__ unsigned cur[NBKT_G];
    __shared__ float    pool[TT];
    __shared__ unsigned wsum[4];

    const int bid = blockIdx.x;
    const int row = ((bid & 7) << 10) | (bid >> 3);
    const int b = row >> 7, c = row & (CC - 1);
    const float* xrow = x + (size_t)b * TT * CC + c;
    const int tid = threadIdx.x;
    const int lane = tid & 63, wid = tid >> 6;

    float vv[16];
    #pragma unroll
    for (int j = 0; j < 16; ++j)
        vv[j] = xrow[(size_t)((j << 8) + tid) * CC];

    *(uint4*)&hist[tid << 2] = make_uint4(0u, 0u, 0u, 0u);
    __syncthreads();

    #pragma unroll
    for (int j = 0; j < 16; ++j) {
        int bk = (int)((vv[j] + 5.0f) * 102.4f);
        bk = bk < 0 ? 0 : (bk > NBKT_G - 1 ? NBKT_G - 1 : bk);
        atomicAdd(&hist[bk], 1u);
    }
    __syncthreads();

    uint4 h = *(uint4*)&hist[tid << 2];
    unsigned S = h.x + h.y + h.z + h.w;
    unsigned incl = S;
    #pragma unroll
    for (int off = 1; off < 64; off <<= 1) {
        unsigned n = __shfl_up(incl, off, 64);
        if (lane >= off) incl += n;
    }
    if (lane == 63) wsum[wid] = incl;
    __syncthreads();
    unsigned base = incl - S;
    for (int w = 0; w < wid; ++w) base += wsum[w];
    {
        unsigned c0 = base, c1 = c0 + h.x, c2 = c1 + h.y, c3 = c2 + h.z;
        *(uint4*)&cum[tid << 2] = make_uint4(c0, c1, c2, c3);
        *(uint4*)&cur[tid << 2] = make_uint4(c0, c1, c2, c3);
    }
    __syncthreads();

    #pragma unroll
    for (int j = 0; j < 16; ++j) {
        int bk = (int)((vv[j] + 5.0f) * 102.4f);
        bk = bk < 0 ? 0 : (bk > NBKT_G - 1 ? NBKT_G - 1 : bk);
        unsigned p = atomicAdd(&cur[bk], 1u);
        pool[p] = vv[j];
    }
    __syncthreads();

    if (tid < 128) {
        const int q = tid >> 1;
        const int r = (q << 6) + 31 + (tid & 1);
        int pos = 0;
        #pragma unroll
        for (int step = 512; step >= 1; step >>= 1) {
            int np = pos + step;
            if (np <= NBKT_G - 1 && (int)cum[np] <= r) pos = np;
        }
        const int segbase = (int)cum[pos];
        const int L = (int)hist[pos];
        const int k = r - segbase;
        const float* seg = &pool[segbase];

        float ans = 0.0f;
        for (int i = 0; i < L; ++i) {
            float vi = seg[i];
            int rk = 0;
            for (int jj = 0; jj < L; ++jj) {
                float vj = seg[jj];
                rk += (vj < vi) || (vj == vi && jj < i);
            }
            if (rk == k) { ans = vi; break; }
        }
        float vo = __shfl_xor(ans, 1, 64);
        if ((tid & 1) == 0)
            qtab[(size_t)row * NQ + q] = (ans + vo) * 0.5f;
    }
}

// ---------------- Kernel 2: CDF interp + probit (register-pivot search) ----------------
__global__ __launch_bounds__(256) void apply_kernel(const float* __restrict__ x,
                                                    const float* __restrict__ qtab,
                                                    float* __restrict__ out) {
    __shared__ float qtT[NQ][64];
    const int b   = blockIdx.x;
    const int tch = blockIdx.y;
    const int ch  = blockIdx.z;
    const int tid = threadIdx.x;

    const float* qsrc = qtab + ((size_t)b * CC + (size_t)ch * 64) * NQ;
    for (int i = tid; i < 64 * NQ; i += 256) {
        int cl = i >> 6, k = i & 63;
        qtT[k][cl ^ k] = qsrc[i];
    }
    __syncthreads();

    const int myc = tid & 63;
    const int trow0 = tid >> 6;
    const size_t base = (size_t)b * TT * CC + (size_t)tch * TCH2 * CC
                      + (size_t)ch * 64;
    const float* xp = x + base;
    float* op = out + base;
    const float invq = 1.0f / (float)NQ;

    float pv0 = qtT[7][myc ^ 7],   pv1 = qtT[15][myc ^ 15];
    float pv2 = qtT[23][myc ^ 23], pv3 = qtT[31][myc ^ 31];
    float pv4 = qtT[39][myc ^ 39], pv5 = qtT[47][myc ^ 47];
    float pv6 = qtT[55][myc ^ 55];

    #pragma unroll
    for (int g = 0; g < 4; ++g) {
        float v[8];
        int   pos[8];
        int   off[8];
        #pragma unroll
        for (int e = 0; e < 8; ++e) {
            int t = trow0 + 4 * (g * 8 + e);
            off[e] = t * CC + myc;
            v[e] = xp[off[e]];
        }

        #pragma unroll
        for (int e = 0; e < 8; ++e) {
            int p = (pv3 <= v[e]) ? 32 : 0;
            float p16 = (p == 0) ? pv1 : pv5;
            p += (p16 <= v[e]) ? 16 : 0;
            float p8 = (p == 0) ? pv0 : (p == 16) ? pv2 : (p == 32) ? pv4 : pv6;
            p += (p8 <= v[e]) ? 8 : 0;
            pos[e] = p;
        }

        #pragma unroll
        for (int step = 4; step >= 1; step >>= 1) {
            float pr[8];
            #pragma unroll
            for (int e = 0; e < 8; ++e) {
                int np = pos[e] + step - 1;
                pr[e] = qtT[np][myc ^ np];
            }
            #pragma unroll
            for (int e = 0; e < 8; ++e)
                if (pr[e] <= v[e]) pos[e] += step;
        }

        float x0[8], x1[8];
        #pragma unroll
        for (int e = 0; e < 8; ++e) {
            int idx = pos[e];
            idx = idx < 1 ? 1 : (idx > NQ - 1 ? NQ - 1 : idx);
            pos[e] = idx;
            x0[e] = qtT[idx - 1][myc ^ (idx - 1)];
            x1[e] = qtT[idx][myc ^ idx];
        }

        #pragma unroll
        for (int e = 0; e < 8; ++e) {
            const float y0 = ((float)pos[e] - 0.5f) * invq;
            const float rcp = __builtin_amdgcn_rcpf(fmaxf(x1[e] - x0[e], 1e-12f));
            float p = fmaf(invq * rcp, v[e] - x0[e], y0);
            p = fminf(fmaxf(p, 1e-6f), 1.0f - 1e-6f);

            const float xx = 2.0f * p - 1.0f;
            float w = -__logf((1.0f - xx) * (1.0f + xx));
            float z;
            if (w < 5.0f) {
                float ww = w - 2.5f;
                z = 2.81022636e-08f;
                z = fmaf(z, ww, 3.43273939e-07f);
                z = fmaf(z, ww, -3.5233877e-06f);
                z = fmaf(z, ww, -4.39150654e-06f);
                z = fmaf(z, ww, 0.00021858087f);
                z = fmaf(z, ww, -0.00125372503f);
                z = fmaf(z, ww, -0.00417768164f);
                z = fmaf(z, ww, 0.246640727f);
                z = fmaf(z, ww, 1.50140941f);
            } else {
                float ww = sqrtf(w) - 3.0f;
                z = -0.000200214257f;
                z = fmaf(z, ww, 0.000100950558f);
                z = fmaf(z, ww, 0.00134934322f);
                z = fmaf(z, ww, -0.00367342844f);
                z = fmaf(z, ww, 0.00573950773f);
                z = fmaf(z, ww, -0.0076224613f);
                z = fmaf(z, ww, 0.00943887047f);
                z = fmaf(z, ww, 1.00167406f);
                z = fmaf(z, ww, 2.83297682f);
            }
            op[off[e]] = z * xx * 1.4142135623730951f;
        }
    }
}

extern "C" void kernel_launch(void* const* d_in, const int* in_sizes, int n_in,
                              void* d_out, int out_size, void* d_ws, size_t ws_size,
                              hipStream_t stream) {
    const float* x = (const float*)d_in[0];
    float* out = (float*)d_out;
    float* qtab = (float*)d_ws;                          // 2 MB
    const size_t qtab_bytes = (size_t)BB * CC * NQ * 4;
    const size_t xT_bytes   = (size_t)BB * CC * TT * 4;  // 128 MB

    if (ws_size >= qtab_bytes + xT_bytes) {
        float* xT = (float*)((char*)d_ws + qtab_bytes);
        dim3 tgrid(2, 64, BB);
        transpose_kernel<<<tgrid, 256, 0, stream>>>(x, xT);
        bucket_quantile_W<<<BB * CC / 4, 256, 0, stream>>>(xT, qtab);
    } else {
        bucket_quantile_G<<<BB * CC, 256, 0, stream>>>(x, qtab);
    }
    dim3 grid(BB, TT / TCH2, 2);
    apply_kernel<<<grid, 256, 0, stream>>>(x, qtab, out);
}

// Round 19
// 211.182 us; speedup vs baseline: 2.1445x; 2.1445x over previous
//
#include <hip/hip_runtime.h>
#include <math.h>

#define BB 64
#define TT 4096
#define CC 128
#define NQ 64
#define TCH2 128  // t-rows per apply block (c is split 2-way)
#define NBKT 2048 // bins for transposed-path select
#define NBKT_G 1024

// ---------------- Kernel 0: transpose x (B,T,C) -> xT (B,C,T) ----------------
__global__ __launch_bounds__(256) void transpose_kernel(const float* __restrict__ x,
                                                        float* __restrict__ xT) {
    __shared__ float tile[64][65];
    const int cb = blockIdx.x;
    const int tb = blockIdx.y;
    const int b  = blockIdx.z;
    const int tid = threadIdx.x;
    const int q = tid >> 6;
    const int l = tid & 63;

    const float* xs = x + ((size_t)b * TT + (size_t)tb * 64) * CC + (size_t)cb * 64;
    #pragma unroll
    for (int j = 0; j < 16; ++j) {
        int tl = q * 16 + j;
        tile[tl][l] = xs[(size_t)tl * CC + l];
    }
    __syncthreads();
    float* xd = xT + ((size_t)b * CC + (size_t)cb * 64) * TT + (size_t)tb * 64;
    #pragma unroll
    for (int j = 0; j < 16; ++j) {
        int cl = q * 16 + j;
        xd[(size_t)cl * TT + l] = tile[l][cl];
    }
}

// ---------------- Kernel 1 (fast path): filtered bucket select, slim LDS ----------------
// R13-proven structure; histogram counts PACKED 2-per-u32 (u16 fields, counts
// <=4096 so no cross-field carry) to halve hist zero-cost and bank pressure.
__global__ __launch_bounds__(256) void bucket_quantile_T(const float* __restrict__ xT,
                                                         float* __restrict__ qtab) {
    __shared__ unsigned       A[NBKT];         // packed hist (words 0..1023) -> pool
    __shared__ unsigned short cum16[NBKT + 2]; // exclusive prefix + sentinel
    __shared__ unsigned char  flag8[NBKT];     // fid or 0xFF
    __shared__ unsigned short rankinfo[128];   // half-rank -> bin
    __shared__ unsigned short pb16[132];       // fid -> pool base
    __shared__ unsigned       cur2[132];       // fid -> running cursor
    __shared__ unsigned       wsum[4], wsum2[4];

    const int row = blockIdx.x;                // = b*CC + c
    const float* xrow = xT + (size_t)row * TT;
    const int tid = threadIdx.x, lane = tid & 63, wid = tid >> 6;

    // contiguous vector load: 16 elements per thread
    float vv[16];
    #pragma unroll
    for (int j = 0; j < 4; ++j) {
        float4 v4 = ((const float4*)xrow)[j * 256 + tid];
        vv[j * 4 + 0] = v4.x; vv[j * 4 + 1] = v4.y;
        vv[j * 4 + 2] = v4.z; vv[j * 4 + 3] = v4.w;
    }

    // zero own 4 packed-hist words (= 8 bins) + sentinel own 8 flags
    *(uint4*)&A[tid * 4]      = make_uint4(0u, 0u, 0u, 0u);
    *(uint2*)&flag8[tid * 8]  = make_uint2(~0u, ~0u);
    __syncthreads();

    // histogram: bucket = clamp(trunc((v+5)*204.8), 0, 2047); packed u16 counts
    #pragma unroll
    for (int j = 0; j < 16; ++j) {
        int bk = (int)((vv[j] + 5.0f) * 204.8f);
        bk = bk < 0 ? 0 : (bk > NBKT - 1 ? NBKT - 1 : bk);
        atomicAdd(&A[bk >> 1], 1u << ((bk & 1) << 4));
    }
    __syncthreads();

    // block-wide exclusive scan (thread owns 8 consecutive bins = 4 words)
    uint4 t4 = *(uint4*)&A[tid * 4];
    unsigned hh[8] = { t4.x & 0xFFFFu, t4.x >> 16, t4.y & 0xFFFFu, t4.y >> 16,
                       t4.z & 0xFFFFu, t4.z >> 16, t4.w & 0xFFFFu, t4.w >> 16 };
    unsigned S = hh[0] + hh[1] + hh[2] + hh[3] + hh[4] + hh[5] + hh[6] + hh[7];
    unsigned incl = S;
    #pragma unroll
    for (int off = 1; off < 64; off <<= 1) {
        unsigned n = __shfl_up(incl, off, 64);
        if (lane >= off) incl += n;
    }
    if (lane == 63) wsum[wid] = incl;
    __syncthreads();
    unsigned base = incl - S;
    for (int w = 0; w < wid; ++w) base += wsum[w];

    unsigned carr[9];
    carr[0] = base;
    #pragma unroll
    for (int i = 0; i < 8; ++i) carr[i + 1] = carr[i] + hh[i];
    #pragma unroll
    for (int bi = 0; bi < 8; ++bi)
        cum16[tid * 8 + bi] = (unsigned short)carr[bi];
    if (tid == 255) cum16[NBKT] = (unsigned short)TT;   // sentinel (=carr[8])

    // mark bins containing target ranks r = 64q+31 / 64q+32
    unsigned flg = 0, myLen = 0, myCnt = 0;
    #pragma unroll
    for (int bi = 0; bi < 8; ++bi) {
        const int cs = (int)carr[bi], ce = (int)carr[bi + 1];
        if (ce > cs) {
            int t0 = cs - 32;
            int q0 = t0 < 0 ? 0 : (t0 >> 6);
            int q1 = (ce >> 6); if (q1 > 63) q1 = 63;
            bool any = false;
            for (int q = q0; q <= q1; ++q) {
                int r1 = (q << 6) + 31, r2 = r1 + 1;
                bool i1 = (r1 >= cs) && (r1 < ce);
                bool i2 = (r2 >= cs) && (r2 < ce);
                if (i1) rankinfo[2 * q]     = (unsigned short)(tid * 8 + bi);
                if (i2) rankinfo[2 * q + 1] = (unsigned short)(tid * 8 + bi);
                any |= (i1 || i2);
            }
            if (any) { flg |= (1u << bi); myLen += (unsigned)(ce - cs); myCnt++; }
        }
    }

    // packed scan (len<<16 | cnt) to assign compact pool slots
    unsigned pk = (myLen << 16) | myCnt;
    unsigned incl2 = pk;
    #pragma unroll
    for (int off = 1; off < 64; off <<= 1) {
        unsigned n = __shfl_up(incl2, off, 64);
        if (lane >= off) incl2 += n;
    }
    if (lane == 63) wsum2[wid] = incl2;
    __syncthreads();
    unsigned b2 = incl2 - pk;
    for (int w = 0; w < wid; ++w) b2 += wsum2[w];
    unsigned lenB = b2 >> 16, cntB = b2 & 0xFFFFu;
    #pragma unroll
    for (int bi = 0; bi < 8; ++bi) {
        if (flg & (1u << bi)) {
            int s = tid * 8 + bi;
            flag8[s] = (unsigned char)cntB;
            pb16[cntB] = (unsigned short)lenB;
            cur2[cntB] = lenB;
            cntB++;
            lenB += carr[bi + 1] - carr[bi];
        }
    }
    __syncthreads();   // hist reads done; A[] becomes the pool from here

    // filtered scatter: only elements in flagged bins (~9%); bound-guarded
    #pragma unroll
    for (int j = 0; j < 16; ++j) {
        int bk = (int)((vv[j] + 5.0f) * 204.8f);
        bk = bk < 0 ? 0 : (bk > NBKT - 1 ? NBKT - 1 : bk);
        unsigned char fl = flag8[bk];
        if (fl != 0xFFu) {
            unsigned p = atomicAdd(&cur2[fl], 1u);
            if (p < (unsigned)NBKT) ((float*)A)[p] = vv[j];
        }
    }
    __syncthreads();

    // selection: exact k-th smallest within each target segment
    if (tid < 128) {
        const int j = tid;
        const int r = ((j >> 1) << 6) + 31 + (j & 1);  // 0-indexed rank
        const int s = rankinfo[j];
        const int cs = (int)cum16[s];
        const int L = (int)cum16[s + 1] - cs;
        const int k = r - cs;
        const unsigned char fid = flag8[s];
        const float* seg = (const float*)A + pb16[fid];

        float ans = 0.0f;
        for (int i = 0; i < L; ++i) {
            float vi = seg[i];
            int rk = 0;
            for (int jj = 0; jj < L; ++jj) {
                float vj = seg[jj];
                rk += (vj < vi) || (vj == vi && jj < i);   // index tie-break
            }
            if (rk == k) { ans = vi; break; }
        }
        float vo = __shfl_xor(ans, 1, 64);
        if ((tid & 1) == 0)
            qtab[(size_t)row * NQ + (j >> 1)] = (ans + vo) * 0.5f;  // frac = 0.5
    }
}

// ---------------- Kernel 1 (fallback, proven R7): strided-gather bucket select ----------------
__global__ __launch_bounds__(256) void bucket_quantile_G(const float* __restrict__ x,
                                                         float* __restrict__ qtab) {
    __shared__ unsigned hist[NBKT_G];
    __shared__ unsigned cum[NBKT_G];
    __shared__ unsigned cur[NBKT_G];
    __shared__ float    pool[TT];
    __shared__ unsigned wsum[4];

    const int bid = blockIdx.x;
    const int row = ((bid & 7) << 10) | (bid >> 3);
    const int b = row >> 7, c = row & (CC - 1);
    const float* xrow = x + (size_t)b * TT * CC + c;
    const int tid = threadIdx.x;
    const int lane = tid & 63, wid = tid >> 6;

    float vv[16];
    #pragma unroll
    for (int j = 0; j < 16; ++j)
        vv[j] = xrow[(size_t)((j << 8) + tid) * CC];

    *(uint4*)&hist[tid << 2] = make_uint4(0u, 0u, 0u, 0u);
    __syncthreads();

    #pragma unroll
    for (int j = 0; j < 16; ++j) {
        int bk = (int)((vv[j] + 5.0f) * 102.4f);
        bk = bk < 0 ? 0 : (bk > NBKT_G - 1 ? NBKT_G - 1 : bk);
        atomicAdd(&hist[bk], 1u);
    }
    __syncthreads();

    uint4 h = *(uint4*)&hist[tid << 2];
    unsigned S = h.x + h.y + h.z + h.w;
    unsigned incl = S;
    #pragma unroll
    for (int off = 1; off < 64; off <<= 1) {
        unsigned n = __shfl_up(incl, off, 64);
        if (lane >= off) incl += n;
    }
    if (lane == 63) wsum[wid] = incl;
    __syncthreads();
    unsigned base = incl - S;
    for (int w = 0; w < wid; ++w) base += wsum[w];
    {
        unsigned c0 = base, c1 = c0 + h.x, c2 = c1 + h.y, c3 = c2 + h.z;
        *(uint4*)&cum[tid << 2] = make_uint4(c0, c1, c2, c3);
        *(uint4*)&cur[tid << 2] = make_uint4(c0, c1, c2, c3);
    }
    __syncthreads();

    #pragma unroll
    for (int j = 0; j < 16; ++j) {
        int bk = (int)((vv[j] + 5.0f) * 102.4f);
        bk = bk < 0 ? 0 : (bk > NBKT_G - 1 ? NBKT_G - 1 : bk);
        unsigned p = atomicAdd(&cur[bk], 1u);
        pool[p] = vv[j];
    }
    __syncthreads();

    if (tid < 128) {
        const int q = tid >> 1;
        const int r = (q << 6) + 31 + (tid & 1);
        int pos = 0;
        #pragma unroll
        for (int step = 512; step >= 1; step >>= 1) {
            int np = pos + step;
            if (np <= NBKT_G - 1 && (int)cum[np] <= r) pos = np;
        }
        const int segbase = (int)cum[pos];
        const int L = (int)hist[pos];
        const int k = r - segbase;
        const float* seg = &pool[segbase];

        float ans = 0.0f;
        for (int i = 0; i < L; ++i) {
            float vi = seg[i];
            int rk = 0;
            for (int jj = 0; jj < L; ++jj) {
                float vj = seg[jj];
                rk += (vj < vi) || (vj == vi && jj < i);
            }
            if (rk == k) { ans = vi; break; }
        }
        float vo = __shfl_xor(ans, 1, 64);
        if ((tid & 1) == 0)
            qtab[(size_t)row * NQ + q] = (ans + vo) * 0.5f;
    }
}

// ---------------- Kernel 2: CDF interp + probit (register-pivot search) ----------------
__global__ __launch_bounds__(256) void apply_kernel(const float* __restrict__ x,
                                                    const float* __restrict__ qtab,
                                                    float* __restrict__ out) {
    __shared__ float qtT[NQ][64];
    const int b   = blockIdx.x;
    const int tch = blockIdx.y;
    const int ch  = blockIdx.z;
    const int tid = threadIdx.x;

    const float* qsrc = qtab + ((size_t)b * CC + (size_t)ch * 64) * NQ;
    for (int i = tid; i < 64 * NQ; i += 256) {
        int cl = i >> 6, k = i & 63;
        qtT[k][cl ^ k] = qsrc[i];
    }
    __syncthreads();

    const int myc = tid & 63;
    const int trow0 = tid >> 6;
    const size_t base = (size_t)b * TT * CC + (size_t)tch * TCH2 * CC
                      + (size_t)ch * 64;
    const float* xp = x + base;
    float* op = out + base;
    const float invq = 1.0f / (float)NQ;

    float pv0 = qtT[7][myc ^ 7],   pv1 = qtT[15][myc ^ 15];
    float pv2 = qtT[23][myc ^ 23], pv3 = qtT[31][myc ^ 31];
    float pv4 = qtT[39][myc ^ 39], pv5 = qtT[47][myc ^ 47];
    float pv6 = qtT[55][myc ^ 55];

    #pragma unroll
    for (int g = 0; g < 4; ++g) {
        float v[8];
        int   pos[8];
        int   off[8];
        #pragma unroll
        for (int e = 0; e < 8; ++e) {
            int t = trow0 + 4 * (g * 8 + e);
            off[e] = t * CC + myc;
            v[e] = xp[off[e]];
        }

        #pragma unroll
        for (int e = 0; e < 8; ++e) {
            int p = (pv3 <= v[e]) ? 32 : 0;
            float p16 = (p == 0) ? pv1 : pv5;
            p += (p16 <= v[e]) ? 16 : 0;
            float p8 = (p == 0) ? pv0 : (p == 16) ? pv2 : (p == 32) ? pv4 : pv6;
            p += (p8 <= v[e]) ? 8 : 0;
            pos[e] = p;
        }

        #pragma unroll
        for (int step = 4; step >= 1; step >>= 1) {
            float pr[8];
            #pragma unroll
            for (int e = 0; e < 8; ++e) {
                int np = pos[e] + step - 1;
                pr[e] = qtT[np][myc ^ np];
            }
            #pragma unroll
            for (int e = 0; e < 8; ++e)
                if (pr[e] <= v[e]) pos[e] += step;
        }

        float x0[8], x1[8];
        #pragma unroll
        for (int e = 0; e < 8; ++e) {
            int idx = pos[e];
            idx = idx < 1 ? 1 : (idx > NQ - 1 ? NQ - 1 : idx);
            pos[e] = idx;
            x0[e] = qtT[idx - 1][myc ^ (idx - 1)];
            x1[e] = qtT[idx][myc ^ idx];
        }

        #pragma unroll
        for (int e = 0; e < 8; ++e) {
            const float y0 = ((float)pos[e] - 0.5f) * invq;
            const float rcp = __builtin_amdgcn_rcpf(fmaxf(x1[e] - x0[e], 1e-12f));
            float p = fmaf(invq * rcp, v[e] - x0[e], y0);
            p = fminf(fmaxf(p, 1e-6f), 1.0f - 1e-6f);

            const float xx = 2.0f * p - 1.0f;
            float w = -__logf((1.0f - xx) * (1.0f + xx));
            float z;
            if (w < 5.0f) {
                float ww = w - 2.5f;
                z = 2.81022636e-08f;
                z = fmaf(z, ww, 3.43273939e-07f);
                z = fmaf(z, ww, -3.5233877e-06f);
                z = fmaf(z, ww, -4.39150654e-06f);
                z = fmaf(z, ww, 0.00021858087f);
                z = fmaf(z, ww, -0.00125372503f);
                z = fmaf(z, ww, -0.00417768164f);
                z = fmaf(z, ww, 0.246640727f);
                z = fmaf(z, ww, 1.50140941f);
            } else {
                float ww = sqrtf(w) - 3.0f;
                z = -0.000200214257f;
                z = fmaf(z, ww, 0.000100950558f);
                z = fmaf(z, ww, 0.00134934322f);
                z = fmaf(z, ww, -0.00367342844f);
                z = fmaf(z, ww, 0.00573950773f);
                z = fmaf(z, ww, -0.0076224613f);
                z = fmaf(z, ww, 0.00943887047f);
                z = fmaf(z, ww, 1.00167406f);
                z = fmaf(z, ww, 2.83297682f);
            }
            op[off[e]] = z * xx * 1.4142135623730951f;
        }
    }
}

extern "C" void kernel_launch(void* const* d_in, const int* in_sizes, int n_in,
                              void* d_out, int out_size, void* d_ws, size_t ws_size,
                              hipStream_t stream) {
    const float* x = (const float*)d_in[0];
    float* out = (float*)d_out;
    float* qtab = (float*)d_ws;                          // 2 MB
    const size_t qtab_bytes = (size_t)BB * CC * NQ * 4;
    const size_t xT_bytes   = (size_t)BB * CC * TT * 4;  // 128 MB

    if (ws_size >= qtab_bytes + xT_bytes) {
        float* xT = (float*)((char*)d_ws + qtab_bytes);
        dim3 tgrid(2, 64, BB);
        transpose_kernel<<<tgrid, 256, 0, stream>>>(x, xT);
        bucket_quantile_T<<<BB * CC, 256, 0, stream>>>(xT, qtab);
    } else {
        bucket_quantile_G<<<BB * CC, 256, 0, stream>>>(x, qtab);
    }
    dim3 grid(BB, TT / TCH2, 2);
    apply_kernel<<<grid, 256, 0, stream>>>(x, qtab, out);
}